// Round 1
// baseline (78.368 us; speedup 1.0000x reference)
//
#include <hip/hip_runtime.h>
#include <math.h>

#define Bn   512
#define Tn   50
#define NAn  5
#define NCn  7
#define GHn  16
#define GWn  32
#define CELLS (NAn*GHn*GWn)     // 2560 cells per batch
#define BMW   (CELLS/32)        // 80 bitmap words

__device__ __constant__ float c_aw[NAn] = {1.0f, 2.0f, 3.5f, 5.0f, 8.0f};
__device__ __constant__ float c_ah[NAn] = {1.5f, 3.0f, 4.5f, 6.0f, 10.0f};

__device__ inline float sigm(float v) { return 1.0f / (1.0f + expf(-v)); }

__device__ inline float wred(float v) {
#pragma unroll
  for (int off = 32; off > 0; off >>= 1) v += __shfl_down(v, off, 64);
  return v;
}

// One block per batch. Wave-0 threads (t<50) process targets; all 256 threads
// then stream the 2560 conf cells. 6 accumulators: mse, pos_conf, cls, neg,
// n_pos, neg_cnt.
__global__ __launch_bounds__(256) void k_main(const float* __restrict__ x,
                                              const float* __restrict__ tg,
                                              float* __restrict__ acc)
{
  const int b   = blockIdx.x;
  const int tid = threadIdx.x;

  __shared__ int      s_best[Tn], s_gi[Tn], s_gj[Tn], s_lbl[Tn];
  __shared__ float    s_tx[Tn], s_ty[Tn], s_tw[Tn], s_th[Tn];
  __shared__ unsigned s_val[Tn];
  __shared__ unsigned s_mask[BMW], s_ign[BMW];
  __shared__ float    red[4][6];

  for (int i = tid; i < BMW; i += 256) { s_mask[i] = 0u; s_ign[i] = 0u; }
  __syncthreads();

  if (tid < Tn) {
    const float* tp = tg + ((size_t)b * Tn + tid) * 5;
    float c0 = tp[0], c1 = tp[1], c2 = tp[2], c3 = tp[3], c4 = tp[4];
    bool valid = (c0 + c1 + c2 + c3 + c4) > 0.0f;
    float gx = c1 * (float)GWn, gy = c2 * (float)GHn;
    float gw = c3 * (float)GWn, gh = c4 * (float)GHn;
    float iou[NAn];
    int best = 0; float bestv = -1.0f;
#pragma unroll
    for (int a = 0; a < NAn; ++a) {
      float inter = fminf(gw, c_aw[a]) * fminf(gh, c_ah[a]);
      float u = inter / (gw * gh + c_aw[a] * c_ah[a] - inter + 1e-16f);
      iou[a] = u;
      if (u > bestv) { bestv = u; best = a; }   // first-max like argmax
    }
    int gi = (int)floorf(gx), gj = (int)floorf(gy);
    bool inb = (gi >= 0) && (gi < GWn) && (gj >= 0) && (gj < GHn); // mode='drop'
    s_best[tid] = best; s_gi[tid] = gi; s_gj[tid] = gj;
    s_lbl[tid]  = (int)c0;                      // astype(int32): trunc toward 0
    s_tx[tid] = gx - floorf(gx);
    s_ty[tid] = gy - floorf(gy);
    s_tw[tid] = logf(gw / c_aw[best] + 1e-16f);
    s_th[tid] = logf(gh / c_ah[best] + 1e-16f);
    unsigned ok = (valid && inb) ? 1u : 0u;
    s_val[tid] = ok;
    if (ok) {
      int cell = best * (GHn * GWn) + gj * GWn + gi;
      atomicOr(&s_mask[cell >> 5], 1u << (cell & 31));
#pragma unroll
      for (int a = 0; a < NAn; ++a) if (iou[a] > 0.6f) {
        int ic = a * (GHn * GWn) + gj * GWn + gi;
        atomicOr(&s_ign[ic >> 5], 1u << (ic & 31));
      }
    }
  }
  __syncthreads();

  float v_mse = 0.f, v_pc = 0.f, v_cls = 0.f, v_neg = 0.f, v_np = 0.f, v_nc = 0.f;

  // ---- positive-cell terms (threads t<50) ----
  if (tid < Tn && s_val[tid]) {
    int best = s_best[tid], gi = s_gi[tid], gj = s_gj[tid];
    // last valid target writing this cell wins (numpy sequential scatter)
    bool win = true;
    for (int u = tid + 1; u < Tn; ++u)
      if (s_val[u] && s_best[u] == best && s_gi[u] == gi && s_gj[u] == gj) { win = false; break; }
    // tcls is a set over (cell,label): count each distinct pair once
    int lbl = s_lbl[tid];
    bool pf = (lbl >= 0 && lbl < NCn);
    if (pf) for (int u = 0; u < tid; ++u)
      if (s_val[u] && s_best[u] == best && s_gi[u] == gi && s_gj[u] == gj && s_lbl[u] == lbl) { pf = false; break; }

    size_t base = (((size_t)b * (NAn * 14) + best * 14) * GHn + gj) * GWn + gi;
    if (win) {
      float p0 = x[base + 0 * 512];
      float p1 = x[base + 1 * 512];
      float p2 = x[base + 2 * 512];
      float p3 = x[base + 3 * 512];
      float p6 = x[base + 6 * 512];
      float dx = sigm(p0) - s_tx[tid];
      float dy = sigm(p1) - s_ty[tid];
      float dw = p2 - s_tw[tid];
      float dh = p3 - s_th[tid];
      v_mse = dx * dx + dy * dy + dw * dw + dh * dh;
      v_pc  = -logf(fmaxf(sigm(p6), 1e-12f));
      v_np  = 1.0f;
    }
    if (pf) {
      float s[NCn];
      float m = -1e30f;
#pragma unroll
      for (int k = 0; k < NCn; ++k) {
        s[k] = sigm(x[base + (size_t)(7 + k) * 512]);
        m = fmaxf(m, s[k]);
      }
      float ssum = 0.f;
#pragma unroll
      for (int k = 0; k < NCn; ++k) ssum += expf(s[k] - m);
      v_cls = (m + logf(ssum)) - s[lbl];        // -log_softmax[lbl]
    }
  }

  // ---- negative conf BCE over all cells of this batch ----
  for (int cell = tid; cell < CELLS; cell += 256) {
    unsigned w = s_mask[cell >> 5] | s_ign[cell >> 5];
    if (!((w >> (cell & 31)) & 1u)) {
      int a = cell >> 9;              // / (GH*GW)
      int rest = cell & 511;
      float v = x[((size_t)b * (NAn * 14) + a * 14 + 6) * 512 + rest];
      float q = fmaxf(1.0f - sigm(v), 1e-12f);
      v_neg += -logf(q);
      v_nc  += 1.0f;
    }
  }

  // ---- block reduction, 6 values ----
  float vals[6] = {v_mse, v_pc, v_cls, v_neg, v_np, v_nc};
  int wid = tid >> 6, lane = tid & 63;
#pragma unroll
  for (int k = 0; k < 6; ++k) {
    float r = wred(vals[k]);
    if (lane == 0) red[wid][k] = r;
  }
  __syncthreads();
  if (tid == 0) {
#pragma unroll
    for (int k = 0; k < 6; ++k)
      atomicAdd(&acc[k], red[0][k] + red[1][k] + red[2][k] + red[3][k]);
  }
}

__global__ void k_fin(const float* __restrict__ acc, float* __restrict__ out)
{
  float npos = fmaxf(acc[4], 1.0f);
  float negc = fmaxf(acc[5], 1.0f);
  float loss = acc[0] / npos            // loss_x+y+w+h
             + acc[3] / negc            // neg conf bce
             + acc[1] / npos            // pos conf bce
             + acc[2] / ((float)Bn * npos); // cls
  out[0] = loss;
}

extern "C" void kernel_launch(void* const* d_in, const int* in_sizes, int n_in,
                              void* d_out, int out_size, void* d_ws, size_t ws_size,
                              hipStream_t stream)
{
  const float* x  = (const float*)d_in[0];
  const float* tg = (const float*)d_in[1];
  float* acc = (float*)d_ws;

  hipMemsetAsync(d_ws, 0, 6 * sizeof(float), stream);
  k_main<<<Bn, 256, 0, stream>>>(x, tg, acc);
  k_fin<<<1, 1, 0, stream>>>(acc, (float*)d_out);
}

// Round 2
// 76.992 us; speedup vs baseline: 1.0179x; 1.0179x over previous
//
#include <hip/hip_runtime.h>
#include <math.h>

#define Bn   512
#define Tn   50
#define NAn  5
#define NCn  7
#define GHn  16
#define GWn  32
#define CELLS (NAn*GHn*GWn)       // 2560 cells per batch
#define BMW   (CELLS/32)          // 80 bitmap words
#define SBLK  640                 // streaming blocks (640*256*2 float4 = all conf)
#define NF4   (Bn*NAn*128)        // total float4 in conf planes = 327680
#define TOTAL_CELLS (Bn*CELLS)    // 1310720

__device__ __constant__ float c_aw[NAn] = {1.0f, 2.0f, 3.5f, 5.0f, 8.0f};
__device__ __constant__ float c_ah[NAn] = {1.5f, 3.0f, 4.5f, 6.0f, 10.0f};

__device__ inline float sigm(float v) { return 1.0f / (1.0f + expf(-v)); }
// -log(clip(1 - sigmoid(v), 1e-12)) — must be bit-identical in stream & correction
__device__ inline float negterm(float v) {
  return -logf(fmaxf(1.0f - sigm(v), 1e-12f));
}

__device__ inline float wred(float v) {
#pragma unroll
  for (int off = 32; off > 0; off >>= 1) v += __shfl_down(v, off, 64);
  return v;
}

// acc layout: [0]=mse(x+y+w+h), [1]=pos_conf_bce, [2]=cls, [3]=neg_sum,
//             [4]=n_pos, [5]=neg_count_correction (<=0)
__global__ __launch_bounds__(256) void k_fused(const float* __restrict__ x,
                                               const float* __restrict__ tg,
                                               float* __restrict__ acc)
{
  const int tid = threadIdx.x;

  if (blockIdx.x < SBLK) {
    // ---------- streaming role: full neg-BCE sum over ALL conf cells ----------
    const int gid = blockIdx.x * 256 + tid;
    float v_neg = 0.f;
#pragma unroll
    for (int k = 0; k < 2; ++k) {
      int idx = gid + k * (SBLK * 256);          // < NF4 always
      int plane = idx >> 7;                      // 128 float4 per plane
      int rest  = idx & 127;
      int b = plane / NAn;
      int a = plane - b * NAn;
      size_t off = (((size_t)b * (NAn * 14) + a * 14 + 6) * 512) + rest * 4;
      const float4 v = *reinterpret_cast<const float4*>(x + off);
      v_neg += negterm(v.x) + negterm(v.y) + negterm(v.z) + negterm(v.w);
    }
    __shared__ float red[4];
    float r = wred(v_neg);
    int wid = tid >> 6, lane = tid & 63;
    if (lane == 0) red[wid] = r;
    __syncthreads();
    if (tid == 0) atomicAdd(&acc[3], red[0] + red[1] + red[2] + red[3]);
    return;
  }

  // ---------- target role: one block per batch ----------
  const int b = blockIdx.x - SBLK;

  __shared__ int      s_best[Tn], s_gi[Tn], s_gj[Tn], s_lbl[Tn];
  __shared__ float    s_tx[Tn], s_ty[Tn], s_tw[Tn], s_th[Tn];
  __shared__ unsigned s_val[Tn];
  __shared__ unsigned s_mask[BMW], s_ign[BMW];
  __shared__ float    red6[4][6];

  for (int i = tid; i < BMW; i += 256) { s_mask[i] = 0u; s_ign[i] = 0u; }
  __syncthreads();

  if (tid < Tn) {
    const float* tp = tg + ((size_t)b * Tn + tid) * 5;
    float c0 = tp[0], c1 = tp[1], c2 = tp[2], c3 = tp[3], c4 = tp[4];
    bool valid = (c0 + c1 + c2 + c3 + c4) > 0.0f;
    float gx = c1 * (float)GWn, gy = c2 * (float)GHn;
    float gw = c3 * (float)GWn, gh = c4 * (float)GHn;
    float iou[NAn];
    int best = 0; float bestv = -1.0f;
#pragma unroll
    for (int a = 0; a < NAn; ++a) {
      float inter = fminf(gw, c_aw[a]) * fminf(gh, c_ah[a]);
      float u = inter / (gw * gh + c_aw[a] * c_ah[a] - inter + 1e-16f);
      iou[a] = u;
      if (u > bestv) { bestv = u; best = a; }   // first-max like argmax
    }
    int gi = (int)floorf(gx), gj = (int)floorf(gy);
    bool inb = (gi >= 0) && (gi < GWn) && (gj >= 0) && (gj < GHn); // mode='drop'
    s_best[tid] = best; s_gi[tid] = gi; s_gj[tid] = gj;
    s_lbl[tid]  = (int)c0;
    s_tx[tid] = gx - floorf(gx);
    s_ty[tid] = gy - floorf(gy);
    s_tw[tid] = logf(gw / c_aw[best] + 1e-16f);
    s_th[tid] = logf(gh / c_ah[best] + 1e-16f);
    unsigned ok = (valid && inb) ? 1u : 0u;
    s_val[tid] = ok;
    if (ok) {
      int cell = best * (GHn * GWn) + gj * GWn + gi;
      atomicOr(&s_mask[cell >> 5], 1u << (cell & 31));
#pragma unroll
      for (int a = 0; a < NAn; ++a) if (iou[a] > 0.6f) {
        int ic = a * (GHn * GWn) + gj * GWn + gi;
        atomicOr(&s_ign[ic >> 5], 1u << (ic & 31));
      }
    }
  }
  __syncthreads();

  float v_mse = 0.f, v_pc = 0.f, v_cls = 0.f, v_neg = 0.f, v_np = 0.f, v_nc = 0.f;

  // ---- positive-cell terms (threads t<50) ----
  if (tid < Tn && s_val[tid]) {
    int best = s_best[tid], gi = s_gi[tid], gj = s_gj[tid];
    bool win = true;   // last valid target writing this cell wins
    for (int u = tid + 1; u < Tn; ++u)
      if (s_val[u] && s_best[u] == best && s_gi[u] == gi && s_gj[u] == gj) { win = false; break; }
    int lbl = s_lbl[tid];
    bool pf = (lbl >= 0 && lbl < NCn);   // tcls: each distinct (cell,label) once
    if (pf) for (int u = 0; u < tid; ++u)
      if (s_val[u] && s_best[u] == best && s_gi[u] == gi && s_gj[u] == gj && s_lbl[u] == lbl) { pf = false; break; }

    size_t base = (((size_t)b * (NAn * 14) + best * 14) * GHn + gj) * GWn + gi;
    if (win) {
      float p0 = x[base + 0 * 512];
      float p1 = x[base + 1 * 512];
      float p2 = x[base + 2 * 512];
      float p3 = x[base + 3 * 512];
      float p6 = x[base + 6 * 512];
      float dx = sigm(p0) - s_tx[tid];
      float dy = sigm(p1) - s_ty[tid];
      float dw = p2 - s_tw[tid];
      float dh = p3 - s_th[tid];
      v_mse = dx * dx + dy * dy + dw * dw + dh * dh;
      v_pc  = -logf(fmaxf(sigm(p6), 1e-12f));
      v_np  = 1.0f;
    }
    if (pf) {
      float s[NCn];
      float m = -1e30f;
#pragma unroll
      for (int k = 0; k < NCn; ++k) {
        s[k] = sigm(x[base + (size_t)(7 + k) * 512]);
        m = fmaxf(m, s[k]);
      }
      float ssum = 0.f;
#pragma unroll
      for (int k = 0; k < NCn; ++k) ssum += expf(s[k] - m);
      v_cls = (m + logf(ssum)) - s[lbl];        // -log_softmax[lbl]
    }
  }

  // ---- correction: subtract masked/ignored cells from the full neg sum ----
  for (int w = tid; w < BMW; w += 256) {
    unsigned bits = s_mask[w] | s_ign[w];
    while (bits) {
      int bit = __builtin_ctz(bits);
      bits &= bits - 1;
      int cell = w * 32 + bit;
      int a = cell >> 9;
      int rest = cell & 511;
      float v = x[((size_t)b * (NAn * 14) + a * 14 + 6) * 512 + rest];
      v_neg -= negterm(v);   // bit-identical to streaming term -> exact cancel
      v_nc  -= 1.0f;
    }
  }

  float vals[6] = {v_mse, v_pc, v_cls, v_neg, v_np, v_nc};
  int wid = tid >> 6, lane = tid & 63;
#pragma unroll
  for (int k = 0; k < 6; ++k) {
    float r = wred(vals[k]);
    if (lane == 0) red6[wid][k] = r;
  }
  __syncthreads();
  if (tid == 0) {
#pragma unroll
    for (int k = 0; k < 6; ++k)
      atomicAdd(&acc[k], red6[0][k] + red6[1][k] + red6[2][k] + red6[3][k]);
  }
}

__global__ void k_fin(const float* __restrict__ acc, float* __restrict__ out)
{
  float npos = fmaxf(acc[4], 1.0f);
  float negc = fmaxf((float)TOTAL_CELLS + acc[5], 1.0f);
  float loss = acc[0] / npos                 // loss_x+y+w+h
             + acc[3] / negc                 // neg conf bce
             + acc[1] / npos                 // pos conf bce
             + acc[2] / ((float)Bn * npos);  // cls
  out[0] = loss;
}

extern "C" void kernel_launch(void* const* d_in, const int* in_sizes, int n_in,
                              void* d_out, int out_size, void* d_ws, size_t ws_size,
                              hipStream_t stream)
{
  const float* x  = (const float*)d_in[0];
  const float* tg = (const float*)d_in[1];
  float* acc = (float*)d_ws;

  hipMemsetAsync(d_ws, 0, 6 * sizeof(float), stream);
  k_fused<<<SBLK + Bn, 256, 0, stream>>>(x, tg, acc);
  k_fin<<<1, 1, 0, stream>>>(acc, (float*)d_out);
}